// Round 8
// baseline (105.163 us; speedup 1.0000x reference)
//
#include <hip/hip_runtime.h>

#define N 8192
#define FIN 256
#define FOUT 64
#define ALPHA 0.2f
#define LOG2C 3
#define NCHUNK (1 << LOG2C)
#define CLEN (N >> LOG2C)        // 1024 j per chunk
#define ITERS (CLEN / 64)        // 16

typedef float f32x4 __attribute__((ext_vector_type(4)));
typedef short s16x8 __attribute__((ext_vector_type(8)));

static __device__ __forceinline__ unsigned short f2bf(float x) {
    unsigned u = __float_as_uint(x);
    u += 0x7fffu + ((u >> 16) & 1u);
    return (unsigned short)(u >> 16);
}

// ---------------- Kernel 1: h = input@W + b_lin ---------------------------------------
// hTf layout: 32-j-major tiles, element (f,j) at (j>>5)*2048 + f*32 + (j&31)  [bf16]
__global__ __launch_bounds__(256) void k_linear(
    const float* __restrict__ input, const float* __restrict__ W,
    const float* __restrict__ b_lin, const float* __restrict__ a,
    unsigned short* __restrict__ hTf, float* __restrict__ s1, float* __restrict__ s2,
    unsigned* __restrict__ s2max_enc)
{
    __shared__ float in_sh[16 * FIN];
    __shared__ float hst[64][17];
    int t = threadIdx.x, w = t >> 6, f = t & 63;
    int b = blockIdx.x;
    int i0 = b * 16;

#pragma unroll
    for (int r = 0; r < 4; r++) {
        int row = w * 4 + r;
        *(float4*)&in_sh[row * FIN + f * 4] =
            *(const float4*)(input + (size_t)(i0 + row) * FIN + f * 4);
    }

    float a1v = a[f], a2v = a[FOUT + f];
    float h[4];
#pragma unroll
    for (int r = 0; r < 4; r++) h[r] = b_lin[f];

    for (int k4 = 0; k4 < FIN / 4; k4++) {
        float wv0 = W[(k4 * 4 + 0) * FOUT + f];
        float wv1 = W[(k4 * 4 + 1) * FOUT + f];
        float wv2 = W[(k4 * 4 + 2) * FOUT + f];
        float wv3 = W[(k4 * 4 + 3) * FOUT + f];
#pragma unroll
        for (int r = 0; r < 4; r++) {
            float4 iv = *(const float4*)&in_sh[(w * 4 + r) * FIN + k4 * 4];
            h[r] = fmaf(iv.x, wv0, h[r]);
            h[r] = fmaf(iv.y, wv1, h[r]);
            h[r] = fmaf(iv.z, wv2, h[r]);
            h[r] = fmaf(iv.w, wv3, h[r]);
        }
    }

    float wmax = -1e30f;
#pragma unroll
    for (int r = 0; r < 4; r++) {
        hst[f][w * 4 + r] = h[r];
        float v1 = h[r] * a1v, v2 = h[r] * a2v;
#pragma unroll
        for (int d = 1; d < 64; d <<= 1) { v1 += __shfl_xor(v1, d); v2 += __shfl_xor(v2, d); }
        wmax = fmaxf(wmax, v2);
        if (f == 0) { s1[i0 + w * 4 + r] = v1; s2[i0 + w * 4 + r] = v2; }
    }
    if (f == 0) {
        unsigned u = __float_as_uint(wmax);
        unsigned key = (u & 0x80000000u) ? ~u : (u | 0x80000000u);
        atomicMax(s2max_enc, key);
    }
    __syncthreads();

    int fo = t >> 2, seg = t & 3;
    unsigned lo = f2bf(hst[fo][seg * 4 + 0]) | ((unsigned)f2bf(hst[fo][seg * 4 + 1]) << 16);
    unsigned hi = f2bf(hst[fo][seg * 4 + 2]) | ((unsigned)f2bf(hst[fo][seg * 4 + 3]) << 16);
    int2 v; v.x = (int)lo; v.y = (int)hi;
    size_t base = (size_t)(b >> 1) * 2048 + (size_t)fo * 32 + (b & 1) * 16 + seg * 4;
    *(int2*)(hTf + base) = v;
}

// ---------------- Kernel 2: fused mask + exp + P@H via mfma 16x16x32 ------------------
// Round-7 structure + T3/T4 pipeline: hT staging via global_load_lds (width=16) into a
// double buffer; ONE raw s_barrier per iteration with counted s_waitcnt vmcnt(4) that
// leaves the 4 adj prefetch loads in flight across the barrier. LDS dest is linear;
// the XOR granule swizzle is applied to the per-lane GLOBAL source (rule 21), reads
// keep round-7's verified kgs pattern.

#define PGEN(AV0, AV1, SVP, AFR) do {                                             \
    float4 sv0 = *(const float4*)(SVP);                                           \
    float4 sv1 = *(const float4*)((SVP) + 4);                                     \
    float p0, p1, p2, p3, p4, p5, p6, p7;                                         \
    { float u = s1c + sv0.x; float g = fmaxf(u, fmaf(0.2f, u, c2)); p0 = (AV0.x > 0) ? exp2f(g) : 0.f; } \
    { float u = s1c + sv0.y; float g = fmaxf(u, fmaf(0.2f, u, c2)); p1 = (AV0.y > 0) ? exp2f(g) : 0.f; } \
    { float u = s1c + sv0.z; float g = fmaxf(u, fmaf(0.2f, u, c2)); p2 = (AV0.z > 0) ? exp2f(g) : 0.f; } \
    { float u = s1c + sv0.w; float g = fmaxf(u, fmaf(0.2f, u, c2)); p3 = (AV0.w > 0) ? exp2f(g) : 0.f; } \
    { float u = s1c + sv1.x; float g = fmaxf(u, fmaf(0.2f, u, c2)); p4 = (AV1.x > 0) ? exp2f(g) : 0.f; } \
    { float u = s1c + sv1.y; float g = fmaxf(u, fmaf(0.2f, u, c2)); p5 = (AV1.y > 0) ? exp2f(g) : 0.f; } \
    { float u = s1c + sv1.z; float g = fmaxf(u, fmaf(0.2f, u, c2)); p6 = (AV1.z > 0) ? exp2f(g) : 0.f; } \
    { float u = s1c + sv1.w; float g = fmaxf(u, fmaf(0.2f, u, c2)); p7 = (AV1.w > 0) ? exp2f(g) : 0.f; } \
    dacc += ((p0 + p1) + (p2 + p3)) + ((p4 + p5) + (p6 + p7));                    \
    union { s16x8 v; unsigned u[4]; } pk;                                         \
    asm("v_cvt_pk_bf16_f32 %0, %1, %2" : "=v"(pk.u[0]) : "v"(p0), "v"(p1));       \
    asm("v_cvt_pk_bf16_f32 %0, %1, %2" : "=v"(pk.u[1]) : "v"(p2), "v"(p3));       \
    asm("v_cvt_pk_bf16_f32 %0, %1, %2" : "=v"(pk.u[2]) : "v"(p4), "v"(p5));       \
    asm("v_cvt_pk_bf16_f32 %0, %1, %2" : "=v"(pk.u[3]) : "v"(p6), "v"(p7));       \
    AFR = pk.v;                                                                   \
} while (0)

__global__ __launch_bounds__(256) void k_attn(
    const int* __restrict__ adj, const float* __restrict__ s1g,
    const float* __restrict__ s2g, const unsigned short* __restrict__ hTf,
    const unsigned* __restrict__ s2max_enc,
    float* __restrict__ numP, float* __restrict__ denP)
{
    __shared__ unsigned short hsh[2][4096];             // 2 x 8 KB double buffer
    __shared__ float s2sh[CLEN];                        // 4 KB (pre-scaled by LOG2E)

    const float LOG2E = 1.4426950408889634f;
    int bid = blockIdx.x;
    int chunk = bid & (NCHUNK - 1);
    int rg = bid >> LOG2C;
    int jstart = chunk * CLEN;
    int t = threadIdx.x, w = t >> 6, l = t & 63;
    int l15 = l & 15, kg = l >> 4;
    int kgs = kg ^ ((l15 >> 1) & 3);                    // swizzled k-granule (read side)

    // per-lane DMA source granules: dst[D] = src[swz(D)]  (involution; same layout as
    // round 7's dst[swz(G)] = src[G])
    int D0 = w * 128 + l;
    int D1 = w * 128 + 64 + l;
    int S0 = (D0 & ~3) | ((D0 ^ (D0 >> 3)) & 3);
    int S1 = (D1 & ~3) | ((D1 ^ (D1 >> 3)) & 3);
    const char* srcb = (const char*)(hTf + (size_t)jstart * 64);

    {   // stage scaled s2 slice: 256 threads x float4 = 1024 floats
        float4 sv = ((const float4*)(s2g + jstart))[t];
        sv.x *= LOG2E; sv.y *= LOG2E; sv.z *= LOG2E; sv.w *= LOG2E;
        ((float4*)s2sh)[t] = sv;
    }
    // prologue: DMA stage tile 0 into buf 0
    __builtin_amdgcn_global_load_lds(srcb + (size_t)S0 * 16,
                                     (char*)&hsh[0][0] + w * 2048, 16, 0, 0);
    __builtin_amdgcn_global_load_lds(srcb + (size_t)S1 * 16,
                                     (char*)&hsh[0][0] + w * 2048 + 1024, 16, 0, 0);

    unsigned key = *s2max_enc;
    unsigned su = (key & 0x80000000u) ? (key ^ 0x80000000u) : ~key;
    float s2m = __uint_as_float(su);

    int i0 = rg * 64;
    int i = i0 + w * 16 + l15;                          // this lane's P-row
    float s1v = s1g[i];
    float mx = s1v + s2m; mx = fmaxf(mx, ALPHA * mx);   // leaky(s1+s2max) >= rowmax
    float m2 = mx * LOG2E;
    float s1c = fmaf(s1v, LOG2E, -m2);
    float c2 = -0.8f * m2;

    const int4* adjq = (const int4*)(adj + (size_t)i * N + jstart);
    int4 a0 = adjq[kg * 2 + 0];
    int4 a1 = adjq[kg * 2 + 1];
    int4 a2 = adjq[8 + kg * 2 + 0];
    int4 a3 = adjq[8 + kg * 2 + 1];

    f32x4 acc[4] = {};
    float dacc = 0.f;
    __syncthreads();                                    // prologue drain (once)

#pragma unroll 1
    for (int it = 0; it < ITERS; it++) {
        int cur = it & 1;
        bool more = (it + 1 < ITERS);
        if (more) {
            // issue next tile's DMA stage FIRST (completes under this iter's compute)
            const char* s = srcb + (size_t)(it + 1) * 8192;
            char* d = (char*)&hsh[cur ^ 1][0] + w * 2048;
            __builtin_amdgcn_global_load_lds(s + (size_t)S0 * 16, d, 16, 0, 0);
            __builtin_amdgcn_global_load_lds(s + (size_t)S1 * 16, d + 1024, 16, 0, 0);
        }
        int4 n0, n1, n2, n3;
        if (more) {
            n0 = adjq[(it + 1) * 16 + kg * 2 + 0];
            n1 = adjq[(it + 1) * 16 + kg * 2 + 1];
            n2 = adjq[(it + 1) * 16 + 8 + kg * 2 + 0];
            n3 = adjq[(it + 1) * 16 + 8 + kg * 2 + 1];
        }

        const float* svp = &s2sh[it * 64 + kg * 8];
        const unsigned short* bt = &hsh[cur][0] + l15 * 32 + kgs * 8;
        // ---- half 0: j-subtile 0 (k = 0..31) ----
        {
            s16x8 b0 = *(const s16x8*)(bt);
            s16x8 b1 = *(const s16x8*)(bt + 512);
            s16x8 b2 = *(const s16x8*)(bt + 1024);
            s16x8 b3 = *(const s16x8*)(bt + 1536);
            s16x8 afr;
            PGEN(a0, a1, svp, afr);
            acc[0] = __builtin_amdgcn_mfma_f32_16x16x32_bf16(afr, b0, acc[0], 0, 0, 0);
            acc[1] = __builtin_amdgcn_mfma_f32_16x16x32_bf16(afr, b1, acc[1], 0, 0, 0);
            acc[2] = __builtin_amdgcn_mfma_f32_16x16x32_bf16(afr, b2, acc[2], 0, 0, 0);
            acc[3] = __builtin_amdgcn_mfma_f32_16x16x32_bf16(afr, b3, acc[3], 0, 0, 0);
        }
        // ---- half 1: j-subtile 1 (k = 32..63) ----
        {
            s16x8 b0 = *(const s16x8*)(bt + 2048);
            s16x8 b1 = *(const s16x8*)(bt + 2560);
            s16x8 b2 = *(const s16x8*)(bt + 3072);
            s16x8 b3 = *(const s16x8*)(bt + 3584);
            s16x8 afr;
            PGEN(a2, a3, svp + 32, afr);
            acc[0] = __builtin_amdgcn_mfma_f32_16x16x32_bf16(afr, b0, acc[0], 0, 0, 0);
            acc[1] = __builtin_amdgcn_mfma_f32_16x16x32_bf16(afr, b1, acc[1], 0, 0, 0);
            acc[2] = __builtin_amdgcn_mfma_f32_16x16x32_bf16(afr, b2, acc[2], 0, 0, 0);
            acc[3] = __builtin_amdgcn_mfma_f32_16x16x32_bf16(afr, b3, acc[3], 0, 0, 0);
        }
        if (more) {
            // counted wait: 2 stage loads done; 4 adj prefetch loads STAY in flight.
            // own ds_reads retired (lgkmcnt 0) so next iter's DMA can't race our reads.
            asm volatile("s_waitcnt vmcnt(4) lgkmcnt(0)" ::: "memory");
            __builtin_amdgcn_s_barrier();
            a0 = n0; a1 = n1; a2 = n2; a3 = n3;
        }
    }

    dacc += __shfl_xor(dacc, 16);
    dacc += __shfl_xor(dacc, 32);
    if (l < 16) denP[(size_t)chunk * N + i0 + w * 16 + l] = dacc;
#pragma unroll
    for (int nt = 0; nt < 4; nt++) {
#pragma unroll
        for (int r = 0; r < 4; r++) {
            int orow = w * 16 + kg * 4 + r;   // C layout: row=(l>>4)*4+r, col=l&15
            numP[((size_t)chunk * N + i0 + orow) * FOUT + nt * 16 + l15] = acc[nt][r];
        }
    }
}

// ---------------- Kernel 3: combine chunk partials, divide, add bias ------------------
__global__ __launch_bounds__(256) void k_finalize(
    const float* __restrict__ numP, const float* __restrict__ denP,
    const float* __restrict__ bias, float* __restrict__ out)
{
    int idx = blockIdx.x * 256 + threadIdx.x;
    int i = idx >> 6, f = idx & 63;
    float nsum = 0.f, dsum = 0.f;
#pragma unroll
    for (int c = 0; c < NCHUNK; c++) {
        nsum += numP[(size_t)c * (N * FOUT) + idx];
        dsum += denP[(size_t)c * N + i];
    }
    out[idx] = nsum / dsum + bias[f];
}

extern "C" void kernel_launch(void* const* d_in, const int* in_sizes, int n_in,
                              void* d_out, int out_size, void* d_ws, size_t ws_size,
                              hipStream_t stream)
{
    const float* input = (const float*)d_in[0];
    const int*   adj   = (const int*)d_in[1];
    const float* W     = (const float*)d_in[2];
    const float* b_lin = (const float*)d_in[3];
    const float* a     = (const float*)d_in[4];
    const float* bias  = (const float*)d_in[5];
    float* out = (float*)d_out;

    char* ws = (char*)d_ws;
    unsigned short* hTf = (unsigned short*)ws;                   // 1 MiB
    float* s1    = (float*)(ws + 1048576);                       // 32 KB
    float* s2    = (float*)(ws + 1048576 + 32768);               // 32 KB
    unsigned* s2max_enc = (unsigned*)(ws + 1048576 + 65536);     // 4 B (padded to 256)
    size_t fixed = 1048576 + 65536 + 256;
    float* numP = (float*)(ws + fixed);                          // 8 x 2 MiB
    float* denP = (float*)(ws + fixed + ((size_t)N * FOUT * 4) * NCHUNK);

    hipMemsetAsync(s2max_enc, 0, 4, stream);                     // capture-safe
    hipLaunchKernelGGL(k_linear, dim3(512), dim3(256), 0, stream,
                       input, W, b_lin, a, hTf, s1, s2, s2max_enc);
    hipLaunchKernelGGL(k_attn, dim3((N / 64) * NCHUNK), dim3(256), 0, stream,
                       adj, s1, s2, hTf, s2max_enc, numP, denP);
    hipLaunchKernelGGL(k_finalize, dim3(2048), dim3(256), 0, stream,
                       numP, denP, bias, out);
}